// Round 2
// baseline (927.180 us; speedup 1.0000x reference)
//
#include <hip/hip_runtime.h>
#include <hip/hip_bf16.h>

// GATv2 x2 + BN + pool + MLP for MI355X. Round 2: fp32 correctness baseline.
// Fixes vs Round 1: edge_index/batch are int32 (harness converts int64 -> int),
// and conv1 is head-partitioned into P passes chosen at runtime so the
// workspace layout fits ws_size (heads are independent in GATv2, so this is
// exact). hipMemsetAsync replaced with a zero-fill kernel.

__device__ __forceinline__ float lrelu(float x, float s) { return x > 0.f ? x : s * x; }

__global__ void zero_ints(int* __restrict__ p, int n) {
  const int t = blockIdx.x * blockDim.x + threadIdx.x;
  if (t < n) p[t] = 0;
}

// ---------------- CSR build (by dst, self-loops appended) ----------------
__global__ void edge_hist(const int* __restrict__ ei, int E, int N,
                          int* __restrict__ counts) {
  const int t = blockIdx.x * blockDim.x + threadIdx.x;
  if (t >= E + N) return;
  const int dst = (t < E) ? ei[E + t] : (t - E);
  atomicAdd(&counts[dst], 1);
}

__global__ __launch_bounds__(1024) void scan_counts(const int* __restrict__ counts,
                                                    int* __restrict__ row_ptr,
                                                    int* __restrict__ cursor, int N) {
  __shared__ int sdata[1024];
  const int t = threadIdx.x;
  const int chunk = (N + 1023) / 1024;
  const int s0 = t * chunk;
  const int s1 = min(N, s0 + chunk);
  int lsum = 0;
  for (int i = s0; i < s1; ++i) lsum += counts[i];
  sdata[t] = lsum;
  __syncthreads();
  for (int off = 1; off < 1024; off <<= 1) {
    int v = 0;
    if (t >= off) v = sdata[t - off];
    __syncthreads();
    sdata[t] += v;
    __syncthreads();
  }
  int run = sdata[t] - lsum;  // exclusive prefix of this chunk
  for (int i = s0; i < s1; ++i) {
    row_ptr[i] = run;
    cursor[i] = run;
    run += counts[i];
  }
  if (s0 < N && s1 == N) row_ptr[N] = run;
}

__global__ void edge_scatter(const int* __restrict__ ei, int E, int N,
                             int* __restrict__ cursor, int* __restrict__ col) {
  const int t = blockIdx.x * blockDim.x + threadIdx.x;
  if (t >= E + N) return;
  const int dst = (t < E) ? ei[E + t] : (t - E);
  const int src = (t < E) ? ei[t] : (t - E);
  const int pos = atomicAdd(&cursor[dst], 1);
  col[pos] = src;
}

// ------- GEMM: C[m, 0:W]=x@Bl[:,0:W], C[m, W:2W]=x@Br[:,0:W]; K=256 -------
// Bl/Br row stride = 1024 (full H*C weight matrices, column-offset by caller).
__global__ __launch_bounds__(256) void gemm_xw(const float* __restrict__ A,
                                               const float* __restrict__ Bl,
                                               const float* __restrict__ Br,
                                               float* __restrict__ Cout, int M, int W) {
  __shared__ float As[16][68];
  __shared__ float Bs[16][68];
  const int tid = threadIdx.x;
  const int m_base = blockIdx.y * 64;
  const int n_base = blockIdx.x * 64;
  const float* B = (n_base < W) ? Bl : Br;
  const int n_src = (n_base < W) ? n_base : (n_base - W);
  const int la_m = tid >> 2;        // 0..63
  const int la_k = (tid & 3) * 4;   // 0,4,8,12
  const int lb_k = tid >> 4;        // 0..15
  const int lb_n = (tid & 15) * 4;  // 0..60
  const int m0 = (tid & 15) * 4;
  const int n0 = (tid >> 4) * 4;
  float acc[4][4] = {};
  for (int k0 = 0; k0 < 256; k0 += 16) {
    float4 av = make_float4(0.f, 0.f, 0.f, 0.f);
    const int gm = m_base + la_m;
    if (gm < M) av = *(const float4*)(A + (size_t)gm * 256 + k0 + la_k);
    As[la_k + 0][la_m] = av.x;
    As[la_k + 1][la_m] = av.y;
    As[la_k + 2][la_m] = av.z;
    As[la_k + 3][la_m] = av.w;
    const float4 bv = *(const float4*)(B + (size_t)(k0 + lb_k) * 1024 + n_src + lb_n);
    *(float4*)&Bs[lb_k][lb_n] = bv;
    __syncthreads();
#pragma unroll
    for (int kk = 0; kk < 16; ++kk) {
      const float4 a4 = *(const float4*)&As[kk][m0];
      const float4 b4 = *(const float4*)&Bs[kk][n0];
      acc[0][0] += a4.x * b4.x; acc[0][1] += a4.x * b4.y; acc[0][2] += a4.x * b4.z; acc[0][3] += a4.x * b4.w;
      acc[1][0] += a4.y * b4.x; acc[1][1] += a4.y * b4.y; acc[1][2] += a4.y * b4.z; acc[1][3] += a4.y * b4.w;
      acc[2][0] += a4.z * b4.x; acc[2][1] += a4.z * b4.y; acc[2][2] += a4.z * b4.z; acc[2][3] += a4.z * b4.w;
      acc[3][0] += a4.w * b4.x; acc[3][1] += a4.w * b4.y; acc[3][2] += a4.w * b4.z; acc[3][3] += a4.w * b4.w;
    }
    __syncthreads();
  }
#pragma unroll
  for (int im = 0; im < 4; ++im) {
    const int gm = m_base + m0 + im;
    if (gm < M) {
      const float4 o = make_float4(acc[im][0], acc[im][1], acc[im][2], acc[im][3]);
      *(float4*)(Cout + (size_t)gm * (2 * W) + n_base + n0) = o;
    }
  }
}

// ---- conv1 attention: one block per dst node, W channels (W/4 threads) ----
// xlrp rows: [0:W] = xl for this pass's heads, [W:2W] = xr.
// att/bias pointers pre-offset by pass; h1 pointer pre-offset, row stride 1024.
__global__ __launch_bounds__(256) void conv1_attn(const float* __restrict__ xlrp,
                                                  const int* __restrict__ row_ptr,
                                                  const int* __restrict__ col,
                                                  const float* __restrict__ att,
                                                  const float* __restrict__ bias,
                                                  float* __restrict__ h1, int W) {
  const int i = blockIdx.x;
  const int tid = threadIdx.x;
  const int nt = blockDim.x;  // W/4
  const int f = tid * 4;      // 4 channels/thread; head group = 32 threads
  __shared__ int s_col[256];
  const float4 a4 = *(const float4*)(att + f);
  const float4 xr4 = *(const float4*)(xlrp + (size_t)i * (2 * W) + W + f);
  float m = -3.0e38f, l = 0.f;
  float4 acc = make_float4(0.f, 0.f, 0.f, 0.f);
  const int kb = row_ptr[i];
  const int ke = row_ptr[i + 1];
  for (int base = kb; base < ke; base += nt) {
    const int cnt = min(nt, ke - base);
    if (tid < cnt) s_col[tid] = col[base + tid];
    __syncthreads();
    float4 xc = *(const float4*)(xlrp + (size_t)s_col[0] * (2 * W) + f);
    for (int q = 0; q < cnt; ++q) {
      float4 xn = xc;
      if (q + 1 < cnt) xn = *(const float4*)(xlrp + (size_t)s_col[q + 1] * (2 * W) + f);
      float s = a4.x * lrelu(xc.x + xr4.x, 0.2f)
              + a4.y * lrelu(xc.y + xr4.y, 0.2f)
              + a4.z * lrelu(xc.z + xr4.z, 0.2f)
              + a4.w * lrelu(xc.w + xr4.w, 0.2f);
      // reduce across the 32-lane head group
      s += __shfl_xor(s, 16);
      s += __shfl_xor(s, 8);
      s += __shfl_xor(s, 4);
      s += __shfl_xor(s, 2);
      s += __shfl_xor(s, 1);
      const float mn = fmaxf(m, s);
      const float sc = __expf(m - mn);
      const float p = __expf(s - mn);
      l = l * sc + p;
      acc.x = acc.x * sc + p * xc.x;
      acc.y = acc.y * sc + p * xc.y;
      acc.z = acc.z * sc + p * xc.z;
      acc.w = acc.w * sc + p * xc.w;
      m = mn;
      xc = xn;
    }
    __syncthreads();
  }
  const float inv = 1.f / (l + 1e-16f);
  const float4 bb = *(const float4*)(bias + f);
  const float4 o = make_float4(acc.x * inv + bb.x, acc.y * inv + bb.y,
                               acc.z * inv + bb.z, acc.w * inv + bb.w);
  *(float4*)(h1 + (size_t)i * 1024 + f) = o;
}

// ---------------- BN1 stats ----------------
__global__ __launch_bounds__(256) void bn1_stats(const float* __restrict__ h1,
                                                 float* __restrict__ bsum,
                                                 float* __restrict__ bsq, int N) {
  const int fidx = blockIdx.x * 256 + threadIdx.x;  // 0..1023
  const int chunk = (N + 63) / 64;
  const int r0 = blockIdx.y * chunk;
  const int r1 = min(N, r0 + chunk);
  float s = 0.f, q = 0.f;
  for (int r = r0; r < r1; ++r) {
    const float v = h1[(size_t)r * 1024 + fidx];
    s += v;
    q += v * v;
  }
  atomicAdd(&bsum[fidx], s);
  atomicAdd(&bsq[fidx], q);
}

// ---------------- BN1 apply + lrelu + conv2 projections ----------------
__global__ __launch_bounds__(256) void bn1_proj(const float* __restrict__ h1,
                                                const float* __restrict__ bsum,
                                                const float* __restrict__ bsq,
                                                const float* __restrict__ g1,
                                                const float* __restrict__ be1,
                                                const float* __restrict__ w2l,
                                                const float* __restrict__ w2r,
                                                float* __restrict__ xl2,
                                                float* __restrict__ xr2, int N) {
  const int i = blockIdx.x;
  const int tid = threadIdx.x;
  const int f = tid * 4;
  const float4 h4 = *(const float4*)(h1 + (size_t)i * 1024 + f);
  const float4 s4 = *(const float4*)(bsum + f);
  const float4 q4 = *(const float4*)(bsq + f);
  const float4 g4 = *(const float4*)(g1 + f);
  const float4 b4 = *(const float4*)(be1 + f);
  const float4 wl = *(const float4*)(w2l + f);
  const float4 wr = *(const float4*)(w2r + f);
  const float invN = 1.f / (float)N;
  float pl = 0.f, pr = 0.f;
  {
    float mu, var, rs, v;
    mu = s4.x * invN; var = q4.x * invN - mu * mu; rs = 1.f / sqrtf(var + 1e-5f);
    v = lrelu((h4.x - mu) * rs * g4.x + b4.x, 0.01f); pl += v * wl.x; pr += v * wr.x;
    mu = s4.y * invN; var = q4.y * invN - mu * mu; rs = 1.f / sqrtf(var + 1e-5f);
    v = lrelu((h4.y - mu) * rs * g4.y + b4.y, 0.01f); pl += v * wl.y; pr += v * wr.y;
    mu = s4.z * invN; var = q4.z * invN - mu * mu; rs = 1.f / sqrtf(var + 1e-5f);
    v = lrelu((h4.z - mu) * rs * g4.z + b4.z, 0.01f); pl += v * wl.z; pr += v * wr.z;
    mu = s4.w * invN; var = q4.w * invN - mu * mu; rs = 1.f / sqrtf(var + 1e-5f);
    v = lrelu((h4.w - mu) * rs * g4.w + b4.w, 0.01f); pl += v * wl.w; pr += v * wr.w;
  }
#pragma unroll
  for (int off = 32; off; off >>= 1) {
    pl += __shfl_down(pl, off);
    pr += __shfl_down(pr, off);
  }
  __shared__ float sp[8];
  if ((tid & 63) == 0) {
    sp[tid >> 6] = pl;
    sp[4 + (tid >> 6)] = pr;
  }
  __syncthreads();
  if (tid == 0) {
    xl2[i] = sp[0] + sp[1] + sp[2] + sp[3];
    xr2[i] = sp[4] + sp[5] + sp[6] + sp[7];
  }
}

// ---------------- conv2 attention: one thread per node ----------------
__global__ void conv2_attn(const float* __restrict__ xl2, const float* __restrict__ xr2,
                           const int* __restrict__ row_ptr, const int* __restrict__ col,
                           const float* __restrict__ att2, const float* __restrict__ b2,
                           float* __restrict__ out2, int N) {
  const int i = blockIdx.x * blockDim.x + threadIdx.x;
  if (i >= N) return;
  const float a = att2[0];
  const float xr = xr2[i];
  float m = -3.0e38f, l = 0.f, acc = 0.f;
  const int kb = row_ptr[i];
  const int ke = row_ptr[i + 1];
  for (int k = kb; k < ke; ++k) {
    const float xv = xl2[col[k]];
    const float s = a * lrelu(xv + xr, 0.2f);
    const float mn = fmaxf(m, s);
    const float sc = __expf(m - mn);
    const float p = __expf(s - mn);
    l = l * sc + p;
    acc = acc * sc + p * xv;
    m = mn;
  }
  out2[i] = acc / (l + 1e-16f) + b2[0];
}

// ---------------- BN2 stats ----------------
__global__ void bn2_stats(const float* __restrict__ out2, float* __restrict__ bn2acc, int N) {
  const int i = blockIdx.x * blockDim.x + threadIdx.x;
  const float v = (i < N) ? out2[i] : 0.f;
  float s = v, q = v * v;
#pragma unroll
  for (int off = 32; off; off >>= 1) {
    s += __shfl_down(s, off);
    q += __shfl_down(q, off);
  }
  if ((threadIdx.x & 63) == 0) {
    atomicAdd(&bn2acc[0], s);
    atomicAdd(&bn2acc[1], q);
  }
}

// ---------------- BN2 apply + lrelu + graph mean pool ----------------
__global__ void bn2_pool(const float* __restrict__ out2, const float* __restrict__ bn2acc,
                         const float* __restrict__ g2, const float* __restrict__ be2,
                         const int* __restrict__ batch,
                         float* __restrict__ pool_sum, float* __restrict__ pool_cnt, int N) {
  const int i = blockIdx.x * blockDim.x + threadIdx.x;
  if (i >= N) return;
  const float invN = 1.f / (float)N;
  const float mu = bn2acc[0] * invN;
  const float var = bn2acc[1] * invN - mu * mu;
  const float rs = 1.f / sqrtf(var + 1e-5f);
  const float v = lrelu((out2[i] - mu) * rs * g2[0] + be2[0], 0.01f);
  const int g = batch[i];
  atomicAdd(&pool_sum[g], v);
  atomicAdd(&pool_cnt[g], 1.0f);
}

// ---------------- MLP head ----------------
__global__ void head_mlp(const float* __restrict__ pool_sum, const float* __restrict__ pool_cnt,
                         const float* __restrict__ lw1, const float* __restrict__ lb1,
                         const float* __restrict__ lw2, const float* __restrict__ lb2,
                         float* __restrict__ out) {
  const int g = threadIdx.x;
  if (g >= 64) return;
  const float p = pool_sum[g] / fmaxf(pool_cnt[g], 1.f);
  float acc = 0.f;
  for (int d = 0; d < 128; ++d) {
    float t = p * lw1[d] + lb1[d];
    t = lrelu(t, 0.01f);
    acc += t * lw2[d];
  }
  out[g] = acc + lb2[0];
}

extern "C" void kernel_launch(void* const* d_in, const int* in_sizes, int n_in,
                              void* d_out, int out_size, void* d_ws, size_t ws_size,
                              hipStream_t stream) {
  const float* x = (const float*)d_in[0];
  const int* ei = (const int*)d_in[1];      // int32 per harness convention
  const int* batch = (const int*)d_in[2];   // int32
  const float* w1_l = (const float*)d_in[3];
  const float* w1_r = (const float*)d_in[4];
  const float* att1 = (const float*)d_in[5];
  const float* b1 = (const float*)d_in[6];
  const float* g1 = (const float*)d_in[7];
  const float* be1 = (const float*)d_in[8];
  const float* w2_l = (const float*)d_in[9];
  const float* w2_r = (const float*)d_in[10];
  const float* att2 = (const float*)d_in[11];
  const float* b2 = (const float*)d_in[12];
  const float* g2 = (const float*)d_in[13];
  const float* be2 = (const float*)d_in[14];
  const float* lw1 = (const float*)d_in[15];
  const float* lb1 = (const float*)d_in[16];
  const float* lw2 = (const float*)d_in[17];
  const float* lb2 = (const float*)d_in[18];

  const int N = in_sizes[2];       // 20000
  const int E = in_sizes[1] / 2;   // 320000
  const int ET = E + N;

  // Pick head-partition factor P (conv1 split into P passes of 8/P heads)
  // so the workspace layout fits ws_size. Heads are independent -> exact.
  const size_t AL = 255;
  auto al = [&](size_t b) { return (b + AL) & ~AL; };
  const size_t zbytes = (size_t)N * 4 + 4096 + 4096 + 16 + 256 + 256;
  const size_t fixed = al((size_t)N * 4096)        // h1
                     + 3 * al((size_t)N * 4)       // xl2, xr2, out2
                     + al((size_t)(N + 1) * 4)     // row_ptr
                     + al((size_t)ET * 4)          // col
                     + al((size_t)N * 4)           // cursor
                     + al(zbytes);
  int P = 1;
  while (P < 8 && fixed + al((size_t)N * (8192 / P)) > ws_size) P <<= 1;
  const int W = 1024 / P;  // channels per pass (xl) ; xlr row = 2*W floats

  char* ws = (char*)d_ws;
  size_t off = 0;
  auto alloc = [&](size_t b) { size_t p = off; off += al(b); return p; };
  float* h1 = (float*)(ws + alloc((size_t)N * 4096));
  float* xlrp = (float*)(ws + alloc((size_t)N * (8192 / P)));
  float* xl2 = (float*)(ws + alloc((size_t)N * 4));
  float* xr2 = (float*)(ws + alloc((size_t)N * 4));
  float* out2 = (float*)(ws + alloc((size_t)N * 4));
  int* row_ptr = (int*)(ws + alloc((size_t)(N + 1) * 4));
  int* colb = (int*)(ws + alloc((size_t)ET * 4));
  int* cursor = (int*)(ws + alloc((size_t)N * 4));
  char* zbase = ws + alloc(zbytes);
  int* counts = (int*)zbase;
  float* bn1_sum = (float*)(zbase + (size_t)N * 4);
  float* bn1_sq = (float*)(zbase + (size_t)N * 4 + 4096);
  float* bn2acc = (float*)(zbase + (size_t)N * 4 + 8192);
  float* pool_sum = (float*)(zbase + (size_t)N * 4 + 8192 + 16);
  float* pool_cnt = (float*)(zbase + (size_t)N * 4 + 8192 + 16 + 256);

  const int zn = (int)(zbytes / 4);
  zero_ints<<<(zn + 255) / 256, 256, 0, stream>>>((int*)zbase, zn);

  edge_hist<<<(ET + 255) / 256, 256, 0, stream>>>(ei, E, N, counts);
  scan_counts<<<1, 1024, 0, stream>>>(counts, row_ptr, cursor, N);
  edge_scatter<<<(ET + 255) / 256, 256, 0, stream>>>(ei, E, N, cursor, colb);

  for (int p = 0; p < P; ++p) {
    gemm_xw<<<dim3(2 * W / 64, (N + 63) / 64), 256, 0, stream>>>(
        x, w1_l + p * W, w1_r + p * W, xlrp, N, W);
    conv1_attn<<<N, W / 4, 0, stream>>>(xlrp, row_ptr, colb,
                                        att1 + p * W, b1 + p * W, h1 + p * W, W);
  }

  bn1_stats<<<dim3(4, 64), 256, 0, stream>>>(h1, bn1_sum, bn1_sq, N);
  bn1_proj<<<N, 256, 0, stream>>>(h1, bn1_sum, bn1_sq, g1, be1, w2_l, w2_r, xl2, xr2, N);
  conv2_attn<<<(N + 255) / 256, 256, 0, stream>>>(xl2, xr2, row_ptr, colb, att2, b2, out2, N);
  bn2_stats<<<(N + 255) / 256, 256, 0, stream>>>(out2, bn2acc, N);
  bn2_pool<<<(N + 255) / 256, 256, 0, stream>>>(out2, bn2acc, g2, be2, batch, pool_sum, pool_cnt, N);
  head_mlp<<<1, 64, 0, stream>>>(pool_sum, pool_cnt, lw1, lb1, lw2, lb2, (float*)d_out);
}

// Round 3
// 741.997 us; speedup vs baseline: 1.2496x; 1.2496x over previous
//
#include <hip/hip_runtime.h>
#include <hip/hip_bf16.h>

// GATv2 x2 + BN + pool + MLP for MI355X. Round 3: projection GEMM moved to
// f16 MFMA with 2-term split (hi+lo, 3 partial products folded into one
// K=768 GEMM). Inputs scaled x16 (epilogue /256) so f16 'lo' parts stay
// normal. m97-style staging: global_load_lds width=16 + XOR chunk swizzle.

__device__ __forceinline__ float lrelu(float x, float s) { return x > 0.f ? x : s * x; }

typedef _Float16 half8 __attribute__((ext_vector_type(8)));
typedef _Float16 half4v __attribute__((ext_vector_type(4)));
typedef float f32x4 __attribute__((ext_vector_type(4)));

#define GLOBAL_AS __attribute__((address_space(1)))
#define LDS_AS __attribute__((address_space(3)))

__device__ __forceinline__ void async_copy16(const void* g, void* l) {
  __builtin_amdgcn_global_load_lds((const GLOBAL_AS unsigned int*)g,
                                   (LDS_AS unsigned int*)l, 16, 0, 0);
}

__global__ void zero_ints(int* __restrict__ p, int n) {
  const int t = blockIdx.x * blockDim.x + threadIdx.x;
  if (t < n) p[t] = 0;
}

// ---------------- CSR build (by dst, self-loops appended) ----------------
__global__ void edge_hist(const int* __restrict__ ei, int E, int N,
                          int* __restrict__ counts) {
  const int t = blockIdx.x * blockDim.x + threadIdx.x;
  if (t >= E + N) return;
  const int dst = (t < E) ? ei[E + t] : (t - E);
  atomicAdd(&counts[dst], 1);
}

__global__ __launch_bounds__(1024) void scan_counts(const int* __restrict__ counts,
                                                    int* __restrict__ row_ptr,
                                                    int* __restrict__ cursor, int N) {
  __shared__ int sdata[1024];
  const int t = threadIdx.x;
  const int chunk = (N + 1023) / 1024;
  const int s0 = t * chunk;
  const int s1 = min(N, s0 + chunk);
  int lsum = 0;
  for (int i = s0; i < s1; ++i) lsum += counts[i];
  sdata[t] = lsum;
  __syncthreads();
  for (int off = 1; off < 1024; off <<= 1) {
    int v = 0;
    if (t >= off) v = sdata[t - off];
    __syncthreads();
    sdata[t] += v;
    __syncthreads();
  }
  int run = sdata[t] - lsum;
  for (int i = s0; i < s1; ++i) {
    row_ptr[i] = run;
    cursor[i] = run;
    run += counts[i];
  }
  if (s0 < N && s1 == N) row_ptr[N] = run;
}

__global__ void edge_scatter(const int* __restrict__ ei, int E, int N,
                             int* __restrict__ cursor, int* __restrict__ col) {
  const int t = blockIdx.x * blockDim.x + threadIdx.x;
  if (t >= E + N) return;
  const int dst = (t < E) ? ei[E + t] : (t - E);
  const int src = (t < E) ? ei[t] : (t - E);
  const int pos = atomicAdd(&cursor[dst], 1);
  col[pos] = src;
}

// ---------------- split-f16 conversions (scale x16) ----------------
// A2[m][0:256] = f16(16*x[m][k]) hi ; A2[m][256:512] = f16 lo residual.
__global__ void convert_x(const float* __restrict__ x, _Float16* __restrict__ A2, int M) {
  const int t = blockIdx.x * blockDim.x + threadIdx.x;
  if (t >= M * 64) return;
  const int m = t >> 6;
  const int k4 = (t & 63) * 4;
  const float4 v = *(const float4*)(x + (size_t)m * 256 + k4);
  const float sx = 16.f;
  _Float16 h0 = (_Float16)(v.x * sx), h1 = (_Float16)(v.y * sx),
           h2 = (_Float16)(v.z * sx), h3 = (_Float16)(v.w * sx);
  _Float16 l0 = (_Float16)(v.x * sx - (float)h0), l1 = (_Float16)(v.y * sx - (float)h1),
           l2 = (_Float16)(v.z * sx - (float)h2), l3 = (_Float16)(v.w * sx - (float)h3);
  _Float16* rowp = A2 + (size_t)m * 512;
  *(half4v*)(rowp + k4) = (half4v){h0, h1, h2, h3};
  *(half4v*)(rowp + 256 + k4) = (half4v){l0, l1, l2, l3};
}

// B3[n][k]: k<256 -> hi(16*w[k][col]); 256..512 -> hi again; 512..768 -> lo.
// n<W from w1_l col (colOff+n); else w1_r col (colOff+n-W). Row stride 768.
__global__ void convert_w(const float* __restrict__ wl, const float* __restrict__ wr,
                          _Float16* __restrict__ B3, int colOff, int W) {
  const int k = blockIdx.y;  // 0..255
  const int n = blockIdx.x * blockDim.x + threadIdx.x;
  if (n >= 2 * W) return;
  const float v = 16.f * ((n < W) ? wl[k * 1024 + colOff + n]
                                  : wr[k * 1024 + colOff + (n - W)]);
  const _Float16 h = (_Float16)v;
  const _Float16 l = (_Float16)(v - (float)h);
  _Float16* rowp = B3 + (size_t)n * 768;
  rowp[k] = h;
  rowp[256 + k] = h;
  rowp[512 + k] = l;
}

// ---------------- MFMA GEMM: C[M x Ntot] = (A2 ext) @ (B3)^T / 256 ----------
// K=768 (3 split products). 128x128 tile, BK=64, 4 waves (2x2), each wave
// 64x64 = 4x4 of v_mfma_f32_16x16x32_f16. XOR chunk swizzle in LDS.
__global__ __launch_bounds__(256) void gemm_mfma(const _Float16* __restrict__ A2,
                                                 const _Float16* __restrict__ B3,
                                                 float* __restrict__ C,
                                                 int M, int Ntot) {
  __shared__ __align__(16) _Float16 As[128 * 64];
  __shared__ __align__(16) _Float16 Bs[128 * 64];
  const int tid = threadIdx.x;
  const int lane = tid & 63;
  const int wv = tid >> 6;
  const int wm = wv & 1, wn = wv >> 1;
  const int m_blk = blockIdx.y * 128;
  const int n_blk = blockIdx.x * 128;
  const int row16 = lane & 15, quad = lane >> 4;
  f32x4 acc[4][4] = {};

  for (int kt = 0; kt < 12; ++kt) {
    const int kg = kt * 64;                      // B3 k base
    const int ka = (kg < 512) ? kg : kg - 512;   // A2 col base (hi reused)
#pragma unroll
    for (int j = 0; j < 4; ++j) {
      const int ci = j * 256 + tid;   // chunk 0..1023 (16B units)
      const int row = ci >> 3;
      const int c = ci & 7;
      const int gc = c ^ (row & 7);   // XOR swizzle: LDS[row][c] = G[row][c^s]
      _Float16* ldsA = &As[(j * 256 + wv * 64) * 8];  // wave-uniform base
      _Float16* ldsB = &Bs[(j * 256 + wv * 64) * 8];
      const int growA = min(m_blk + row, M - 1);
      async_copy16(A2 + (size_t)growA * 512 + ka + gc * 8, ldsA);
      async_copy16(B3 + (size_t)(n_blk + row) * 768 + kg + gc * 8, ldsB);
    }
    __syncthreads();
#pragma unroll
    for (int ks = 0; ks < 2; ++ks) {
      half8 af[4], bf[4];
#pragma unroll
      for (int mi = 0; mi < 4; ++mi) {
        const int r = wm * 64 + mi * 16 + row16;
        const int cl = (ks * 4 + quad) ^ (r & 7);
        af[mi] = *(const half8*)&As[r * 64 + cl * 8];
      }
#pragma unroll
      for (int ni = 0; ni < 4; ++ni) {
        const int r = wn * 64 + ni * 16 + row16;
        const int cl = (ks * 4 + quad) ^ (r & 7);
        bf[ni] = *(const half8*)&Bs[r * 64 + cl * 8];
      }
#pragma unroll
      for (int mi = 0; mi < 4; ++mi)
#pragma unroll
        for (int ni = 0; ni < 4; ++ni)
          acc[mi][ni] = __builtin_amdgcn_mfma_f32_16x16x32_f16(af[mi], bf[ni], acc[mi][ni], 0, 0, 0);
    }
    __syncthreads();
  }
  const float inv = 1.f / 256.f;  // undo x16 * x16 scaling
#pragma unroll
  for (int mi = 0; mi < 4; ++mi) {
#pragma unroll
    for (int reg = 0; reg < 4; ++reg) {
      const int r = m_blk + wm * 64 + mi * 16 + quad * 4 + reg;
      if (r < M) {
#pragma unroll
        for (int ni = 0; ni < 4; ++ni) {
          C[(size_t)r * Ntot + n_blk + wn * 64 + ni * 16 + row16] = acc[mi][ni][reg] * inv;
        }
      }
    }
  }
}

// ---- conv1 attention: one block per dst node, W channels (W/4 threads) ----
__global__ __launch_bounds__(256) void conv1_attn(const float* __restrict__ xlrp,
                                                  const int* __restrict__ row_ptr,
                                                  const int* __restrict__ col,
                                                  const float* __restrict__ att,
                                                  const float* __restrict__ bias,
                                                  float* __restrict__ h1, int W) {
  const int i = blockIdx.x;
  const int tid = threadIdx.x;
  const int nt = blockDim.x;  // W/4
  const int f = tid * 4;
  __shared__ int s_col[256];
  const float4 a4 = *(const float4*)(att + f);
  const float4 xr4 = *(const float4*)(xlrp + (size_t)i * (2 * W) + W + f);
  float m = -3.0e38f, l = 0.f;
  float4 acc = make_float4(0.f, 0.f, 0.f, 0.f);
  const int kb = row_ptr[i];
  const int ke = row_ptr[i + 1];
  for (int base = kb; base < ke; base += nt) {
    const int cnt = min(nt, ke - base);
    if (tid < cnt) s_col[tid] = col[base + tid];
    __syncthreads();
    float4 xc = *(const float4*)(xlrp + (size_t)s_col[0] * (2 * W) + f);
    for (int q = 0; q < cnt; ++q) {
      float4 xn = xc;
      if (q + 1 < cnt) xn = *(const float4*)(xlrp + (size_t)s_col[q + 1] * (2 * W) + f);
      float s = a4.x * lrelu(xc.x + xr4.x, 0.2f)
              + a4.y * lrelu(xc.y + xr4.y, 0.2f)
              + a4.z * lrelu(xc.z + xr4.z, 0.2f)
              + a4.w * lrelu(xc.w + xr4.w, 0.2f);
      s += __shfl_xor(s, 16);
      s += __shfl_xor(s, 8);
      s += __shfl_xor(s, 4);
      s += __shfl_xor(s, 2);
      s += __shfl_xor(s, 1);
      const float mn = fmaxf(m, s);
      const float sc = __expf(m - mn);
      const float p = __expf(s - mn);
      l = l * sc + p;
      acc.x = acc.x * sc + p * xc.x;
      acc.y = acc.y * sc + p * xc.y;
      acc.z = acc.z * sc + p * xc.z;
      acc.w = acc.w * sc + p * xc.w;
      m = mn;
      xc = xn;
    }
    __syncthreads();
  }
  const float inv = 1.f / (l + 1e-16f);
  const float4 bb = *(const float4*)(bias + f);
  const float4 o = make_float4(acc.x * inv + bb.x, acc.y * inv + bb.y,
                               acc.z * inv + bb.z, acc.w * inv + bb.w);
  *(float4*)(h1 + (size_t)i * 1024 + f) = o;
}

// ---------------- BN1 stats ----------------
__global__ __launch_bounds__(256) void bn1_stats(const float* __restrict__ h1,
                                                 float* __restrict__ bsum,
                                                 float* __restrict__ bsq, int N) {
  const int fidx = blockIdx.x * 256 + threadIdx.x;
  const int chunk = (N + 63) / 64;
  const int r0 = blockIdx.y * chunk;
  const int r1 = min(N, r0 + chunk);
  float s = 0.f, q = 0.f;
  for (int r = r0; r < r1; ++r) {
    const float v = h1[(size_t)r * 1024 + fidx];
    s += v;
    q += v * v;
  }
  atomicAdd(&bsum[fidx], s);
  atomicAdd(&bsq[fidx], q);
}

// ---------------- BN1 apply + lrelu + conv2 projections ----------------
__global__ __launch_bounds__(256) void bn1_proj(const float* __restrict__ h1,
                                                const float* __restrict__ bsum,
                                                const float* __restrict__ bsq,
                                                const float* __restrict__ g1,
                                                const float* __restrict__ be1,
                                                const float* __restrict__ w2l,
                                                const float* __restrict__ w2r,
                                                float* __restrict__ xl2,
                                                float* __restrict__ xr2, int N) {
  const int i = blockIdx.x;
  const int tid = threadIdx.x;
  const int f = tid * 4;
  const float4 h4 = *(const float4*)(h1 + (size_t)i * 1024 + f);
  const float4 s4 = *(const float4*)(bsum + f);
  const float4 q4 = *(const float4*)(bsq + f);
  const float4 g4 = *(const float4*)(g1 + f);
  const float4 b4 = *(const float4*)(be1 + f);
  const float4 wl = *(const float4*)(w2l + f);
  const float4 wr = *(const float4*)(w2r + f);
  const float invN = 1.f / (float)N;
  float pl = 0.f, pr = 0.f;
  {
    float mu, var, rs, v;
    mu = s4.x * invN; var = q4.x * invN - mu * mu; rs = 1.f / sqrtf(var + 1e-5f);
    v = lrelu((h4.x - mu) * rs * g4.x + b4.x, 0.01f); pl += v * wl.x; pr += v * wr.x;
    mu = s4.y * invN; var = q4.y * invN - mu * mu; rs = 1.f / sqrtf(var + 1e-5f);
    v = lrelu((h4.y - mu) * rs * g4.y + b4.y, 0.01f); pl += v * wl.y; pr += v * wr.y;
    mu = s4.z * invN; var = q4.z * invN - mu * mu; rs = 1.f / sqrtf(var + 1e-5f);
    v = lrelu((h4.z - mu) * rs * g4.z + b4.z, 0.01f); pl += v * wl.z; pr += v * wr.z;
    mu = s4.w * invN; var = q4.w * invN - mu * mu; rs = 1.f / sqrtf(var + 1e-5f);
    v = lrelu((h4.w - mu) * rs * g4.w + b4.w, 0.01f); pl += v * wl.w; pr += v * wr.w;
  }
#pragma unroll
  for (int off = 32; off; off >>= 1) {
    pl += __shfl_down(pl, off);
    pr += __shfl_down(pr, off);
  }
  __shared__ float sp[8];
  if ((tid & 63) == 0) {
    sp[tid >> 6] = pl;
    sp[4 + (tid >> 6)] = pr;
  }
  __syncthreads();
  if (tid == 0) {
    xl2[i] = sp[0] + sp[1] + sp[2] + sp[3];
    xr2[i] = sp[4] + sp[5] + sp[6] + sp[7];
  }
}

// ---------------- conv2 attention: one thread per node ----------------
__global__ void conv2_attn(const float* __restrict__ xl2, const float* __restrict__ xr2,
                           const int* __restrict__ row_ptr, const int* __restrict__ col,
                           const float* __restrict__ att2, const float* __restrict__ b2,
                           float* __restrict__ out2, int N) {
  const int i = blockIdx.x * blockDim.x + threadIdx.x;
  if (i >= N) return;
  const float a = att2[0];
  const float xr = xr2[i];
  float m = -3.0e38f, l = 0.f, acc = 0.f;
  const int kb = row_ptr[i];
  const int ke = row_ptr[i + 1];
  for (int k = kb; k < ke; ++k) {
    const float xv = xl2[col[k]];
    const float s = a * lrelu(xv + xr, 0.2f);
    const float mn = fmaxf(m, s);
    const float sc = __expf(m - mn);
    const float p = __expf(s - mn);
    l = l * sc + p;
    acc = acc * sc + p * xv;
    m = mn;
  }
  out2[i] = acc / (l + 1e-16f) + b2[0];
}

// ---------------- BN2 stats ----------------
__global__ void bn2_stats(const float* __restrict__ out2, float* __restrict__ bn2acc, int N) {
  const int i = blockIdx.x * blockDim.x + threadIdx.x;
  const float v = (i < N) ? out2[i] : 0.f;
  float s = v, q = v * v;
#pragma unroll
  for (int off = 32; off; off >>= 1) {
    s += __shfl_down(s, off);
    q += __shfl_down(q, off);
  }
  if ((threadIdx.x & 63) == 0) {
    atomicAdd(&bn2acc[0], s);
    atomicAdd(&bn2acc[1], q);
  }
}

// ---------------- BN2 apply + lrelu + graph mean pool ----------------
__global__ void bn2_pool(const float* __restrict__ out2, const float* __restrict__ bn2acc,
                         const float* __restrict__ g2, const float* __restrict__ be2,
                         const int* __restrict__ batch,
                         float* __restrict__ pool_sum, float* __restrict__ pool_cnt, int N) {
  const int i = blockIdx.x * blockDim.x + threadIdx.x;
  if (i >= N) return;
  const float invN = 1.f / (float)N;
  const float mu = bn2acc[0] * invN;
  const float var = bn2acc[1] * invN - mu * mu;
  const float rs = 1.f / sqrtf(var + 1e-5f);
  const float v = lrelu((out2[i] - mu) * rs * g2[0] + be2[0], 0.01f);
  const int g = batch[i];
  atomicAdd(&pool_sum[g], v);
  atomicAdd(&pool_cnt[g], 1.0f);
}

// ---------------- MLP head ----------------
__global__ void head_mlp(const float* __restrict__ pool_sum, const float* __restrict__ pool_cnt,
                         const float* __restrict__ lw1, const float* __restrict__ lb1,
                         const float* __restrict__ lw2, const float* __restrict__ lb2,
                         float* __restrict__ out) {
  const int g = threadIdx.x;
  if (g >= 64) return;
  const float p = pool_sum[g] / fmaxf(pool_cnt[g], 1.f);
  float acc = 0.f;
  for (int d = 0; d < 128; ++d) {
    float t = p * lw1[d] + lb1[d];
    t = lrelu(t, 0.01f);
    acc += t * lw2[d];
  }
  out[g] = acc + lb2[0];
}

extern "C" void kernel_launch(void* const* d_in, const int* in_sizes, int n_in,
                              void* d_out, int out_size, void* d_ws, size_t ws_size,
                              hipStream_t stream) {
  const float* x = (const float*)d_in[0];
  const int* ei = (const int*)d_in[1];
  const int* batch = (const int*)d_in[2];
  const float* w1_l = (const float*)d_in[3];
  const float* w1_r = (const float*)d_in[4];
  const float* att1 = (const float*)d_in[5];
  const float* b1 = (const float*)d_in[6];
  const float* g1 = (const float*)d_in[7];
  const float* be1 = (const float*)d_in[8];
  const float* w2_l = (const float*)d_in[9];
  const float* w2_r = (const float*)d_in[10];
  const float* att2 = (const float*)d_in[11];
  const float* b2 = (const float*)d_in[12];
  const float* g2 = (const float*)d_in[13];
  const float* be2 = (const float*)d_in[14];
  const float* lw1 = (const float*)d_in[15];
  const float* lb1 = (const float*)d_in[16];
  const float* lw2 = (const float*)d_in[17];
  const float* lb2 = (const float*)d_in[18];

  const int N = in_sizes[2];
  const int E = in_sizes[1] / 2;
  const int ET = E + N;

  const size_t AL = 255;
  auto al = [&](size_t b) { return (b + AL) & ~AL; };
  const size_t zbytes = (size_t)N * 4 + 4096 + 4096 + 16 + 256 + 256;
  const size_t fixedNoXlr = al((size_t)N * 4096)     // h1
                          + 3 * al((size_t)N * 4)    // xl2, xr2, out2
                          + al((size_t)(N + 1) * 4)  // row_ptr
                          + al((size_t)ET * 4)       // col
                          + al((size_t)N * 4)        // cursor
                          + al(zbytes);
  const size_t a2b = al((size_t)N * 512 * 2);
  int P = 1;
  while (P < 8) {
    const size_t xlrb = al((size_t)N * (8192 / P));
    const size_t b3b = al((size_t)(2 * (1024 / P)) * 768 * 2);
    const size_t extra = (P == 1) ? 0 : (a2b + b3b);
    if (fixedNoXlr + xlrb + extra <= ws_size) break;
    P <<= 1;
  }
  const int W = 1024 / P;

  char* ws = (char*)d_ws;
  size_t off = 0;
  auto alloc = [&](size_t b) { size_t p = off; off += al(b); return p; };
  float* h1 = (float*)(ws + alloc((size_t)N * 4096));
  float* xlrp = (float*)(ws + alloc((size_t)N * (8192 / P)));
  float* xl2 = (float*)(ws + alloc((size_t)N * 4));
  float* xr2 = (float*)(ws + alloc((size_t)N * 4));
  float* out2 = (float*)(ws + alloc((size_t)N * 4));
  int* row_ptr = (int*)(ws + alloc((size_t)(N + 1) * 4));
  int* colb = (int*)(ws + alloc((size_t)ET * 4));
  int* cursor = (int*)(ws + alloc((size_t)N * 4));
  char* zbase = ws + alloc(zbytes);
  int* counts = (int*)zbase;
  float* bn1_sum = (float*)(zbase + (size_t)N * 4);
  float* bn1_sq = (float*)(zbase + (size_t)N * 4 + 4096);
  float* bn2acc = (float*)(zbase + (size_t)N * 4 + 8192);
  float* pool_sum = (float*)(zbase + (size_t)N * 4 + 8192 + 16);
  float* pool_cnt = (float*)(zbase + (size_t)N * 4 + 8192 + 16 + 256);

  _Float16 *A2, *B3;
  if (P == 1) {  // h1 is dead until conv1_attn -> alias A2/B3 into it
    A2 = (_Float16*)h1;
    B3 = (_Float16*)((char*)h1 + a2b);
  } else {
    A2 = (_Float16*)(ws + alloc((size_t)N * 512 * 2));
    B3 = (_Float16*)(ws + alloc((size_t)(2 * W) * 768 * 2));
  }

  const int zn = (int)(zbytes / 4);
  zero_ints<<<(zn + 255) / 256, 256, 0, stream>>>((int*)zbase, zn);

  edge_hist<<<(ET + 255) / 256, 256, 0, stream>>>(ei, E, N, counts);
  scan_counts<<<1, 1024, 0, stream>>>(counts, row_ptr, cursor, N);
  edge_scatter<<<(ET + 255) / 256, 256, 0, stream>>>(ei, E, N, cursor, colb);

  convert_x<<<(N * 64 + 255) / 256, 256, 0, stream>>>(x, A2, N);
  for (int p = 0; p < P; ++p) {
    convert_w<<<dim3((2 * W + 255) / 256, 256), 256, 0, stream>>>(w1_l, w1_r, B3, p * W, W);
    gemm_mfma<<<dim3(2 * W / 128, (N + 127) / 128), 256, 0, stream>>>(A2, B3, xlrp, N, 2 * W);
    conv1_attn<<<N, W / 4, 0, stream>>>(xlrp, row_ptr, colb,
                                        att1 + p * W, b1 + p * W, h1 + p * W, W);
  }

  bn1_stats<<<dim3(4, 64), 256, 0, stream>>>(h1, bn1_sum, bn1_sq, N);
  bn1_proj<<<N, 256, 0, stream>>>(h1, bn1_sum, bn1_sq, g1, be1, w2_l, w2_r, xl2, xr2, N);
  conv2_attn<<<(N + 255) / 256, 256, 0, stream>>>(xl2, xr2, row_ptr, colb, att2, b2, out2, N);
  bn2_stats<<<(N + 255) / 256, 256, 0, stream>>>(out2, bn2acc, N);
  bn2_pool<<<(N + 255) / 256, 256, 0, stream>>>(out2, bn2acc, g2, be2, batch, pool_sum, pool_cnt, N);
  head_mlp<<<1, 64, 0, stream>>>(pool_sum, pool_cnt, lw1, lb1, lw2, lb2, (float*)d_out);
}

// Round 4
// 640.537 us; speedup vs baseline: 1.4475x; 1.1584x over previous
//
#include <hip/hip_runtime.h>
#include <hip/hip_bf16.h>

// GATv2 x2 + BN + pool + MLP for MI355X. Round 4: xlr stored as f16
// (GEMM epilogue converts), conv1_attn gathers half8 (16B/lane) -> halves
// the per-edge gather bytes (the measured bottleneck: 692 MB HBM fetch).
// GEMM stays 3-term split f16 MFMA (fp32-accurate); only storage rounding
// (2^-11) is injected. Lazy-rescale online softmax in conv1.

__device__ __forceinline__ float lrelu(float x, float s) { return x > 0.f ? x : s * x; }

typedef _Float16 half8 __attribute__((ext_vector_type(8)));
typedef _Float16 half4v __attribute__((ext_vector_type(4)));
typedef float f32x4 __attribute__((ext_vector_type(4)));

#define GLOBAL_AS __attribute__((address_space(1)))
#define LDS_AS __attribute__((address_space(3)))

__device__ __forceinline__ void async_copy16(const void* g, void* l) {
  __builtin_amdgcn_global_load_lds((const GLOBAL_AS unsigned int*)g,
                                   (LDS_AS unsigned int*)l, 16, 0, 0);
}

__global__ void zero_ints(int* __restrict__ p, int n) {
  const int t = blockIdx.x * blockDim.x + threadIdx.x;
  if (t < n) p[t] = 0;
}

// ---------------- CSR build (by dst, self-loops appended) ----------------
__global__ void edge_hist(const int* __restrict__ ei, int E, int N,
                          int* __restrict__ counts) {
  const int t = blockIdx.x * blockDim.x + threadIdx.x;
  if (t >= E + N) return;
  const int dst = (t < E) ? ei[E + t] : (t - E);
  atomicAdd(&counts[dst], 1);
}

__global__ __launch_bounds__(1024) void scan_counts(const int* __restrict__ counts,
                                                    int* __restrict__ row_ptr,
                                                    int* __restrict__ cursor, int N) {
  __shared__ int sdata[1024];
  const int t = threadIdx.x;
  const int chunk = (N + 1023) / 1024;
  const int s0 = t * chunk;
  const int s1 = min(N, s0 + chunk);
  int lsum = 0;
  for (int i = s0; i < s1; ++i) lsum += counts[i];
  sdata[t] = lsum;
  __syncthreads();
  for (int off = 1; off < 1024; off <<= 1) {
    int v = 0;
    if (t >= off) v = sdata[t - off];
    __syncthreads();
    sdata[t] += v;
    __syncthreads();
  }
  int run = sdata[t] - lsum;
  for (int i = s0; i < s1; ++i) {
    row_ptr[i] = run;
    cursor[i] = run;
    run += counts[i];
  }
  if (s0 < N && s1 == N) row_ptr[N] = run;
}

__global__ void edge_scatter(const int* __restrict__ ei, int E, int N,
                             int* __restrict__ cursor, int* __restrict__ col) {
  const int t = blockIdx.x * blockDim.x + threadIdx.x;
  if (t >= E + N) return;
  const int dst = (t < E) ? ei[E + t] : (t - E);
  const int src = (t < E) ? ei[t] : (t - E);
  const int pos = atomicAdd(&cursor[dst], 1);
  col[pos] = src;
}

// ---------------- split-f16 conversions (scale x16) ----------------
__global__ void convert_x(const float* __restrict__ x, _Float16* __restrict__ A2, int M) {
  const int t = blockIdx.x * blockDim.x + threadIdx.x;
  if (t >= M * 64) return;
  const int m = t >> 6;
  const int k4 = (t & 63) * 4;
  const float4 v = *(const float4*)(x + (size_t)m * 256 + k4);
  const float sx = 16.f;
  _Float16 h0 = (_Float16)(v.x * sx), h1 = (_Float16)(v.y * sx),
           h2 = (_Float16)(v.z * sx), h3 = (_Float16)(v.w * sx);
  _Float16 l0 = (_Float16)(v.x * sx - (float)h0), l1 = (_Float16)(v.y * sx - (float)h1),
           l2 = (_Float16)(v.z * sx - (float)h2), l3 = (_Float16)(v.w * sx - (float)h3);
  _Float16* rowp = A2 + (size_t)m * 512;
  *(half4v*)(rowp + k4) = (half4v){h0, h1, h2, h3};
  *(half4v*)(rowp + 256 + k4) = (half4v){l0, l1, l2, l3};
}

__global__ void convert_w(const float* __restrict__ wl, const float* __restrict__ wr,
                          _Float16* __restrict__ B3, int colOff, int W) {
  const int k = blockIdx.y;  // 0..255
  const int n = blockIdx.x * blockDim.x + threadIdx.x;
  if (n >= 2 * W) return;
  const float v = 16.f * ((n < W) ? wl[k * 1024 + colOff + n]
                                  : wr[k * 1024 + colOff + (n - W)]);
  const _Float16 h = (_Float16)v;
  const _Float16 l = (_Float16)(v - (float)h);
  _Float16* rowp = B3 + (size_t)n * 768;
  rowp[k] = h;
  rowp[256 + k] = h;
  rowp[512 + k] = l;
}

// ------- MFMA GEMM: xlr[M x Ntot] (f16) = ((A2 ext) @ B3^T) / 256 ----------
__global__ __launch_bounds__(256) void gemm_mfma(const _Float16* __restrict__ A2,
                                                 const _Float16* __restrict__ B3,
                                                 _Float16* __restrict__ C,
                                                 int M, int Ntot) {
  __shared__ __align__(16) _Float16 As[128 * 64];
  __shared__ __align__(16) _Float16 Bs[128 * 64];
  const int tid = threadIdx.x;
  const int lane = tid & 63;
  const int wv = tid >> 6;
  const int wm = wv & 1, wn = wv >> 1;
  const int m_blk = blockIdx.y * 128;
  const int n_blk = blockIdx.x * 128;
  const int row16 = lane & 15, quad = lane >> 4;
  f32x4 acc[4][4] = {};

  for (int kt = 0; kt < 12; ++kt) {
    const int kg = kt * 64;
    const int ka = (kg < 512) ? kg : kg - 512;  // hi cols reused for hi*lo term
#pragma unroll
    for (int j = 0; j < 4; ++j) {
      const int ci = j * 256 + tid;
      const int row = ci >> 3;
      const int c = ci & 7;
      const int gc = c ^ (row & 7);
      _Float16* ldsA = &As[(j * 256 + wv * 64) * 8];
      _Float16* ldsB = &Bs[(j * 256 + wv * 64) * 8];
      const int growA = min(m_blk + row, M - 1);
      async_copy16(A2 + (size_t)growA * 512 + ka + gc * 8, ldsA);
      async_copy16(B3 + (size_t)(n_blk + row) * 768 + kg + gc * 8, ldsB);
    }
    __syncthreads();
#pragma unroll
    for (int ks = 0; ks < 2; ++ks) {
      half8 af[4], bf[4];
#pragma unroll
      for (int mi = 0; mi < 4; ++mi) {
        const int r = wm * 64 + mi * 16 + row16;
        const int cl = (ks * 4 + quad) ^ (r & 7);
        af[mi] = *(const half8*)&As[r * 64 + cl * 8];
      }
#pragma unroll
      for (int ni = 0; ni < 4; ++ni) {
        const int r = wn * 64 + ni * 16 + row16;
        const int cl = (ks * 4 + quad) ^ (r & 7);
        bf[ni] = *(const half8*)&Bs[r * 64 + cl * 8];
      }
#pragma unroll
      for (int mi = 0; mi < 4; ++mi)
#pragma unroll
        for (int ni = 0; ni < 4; ++ni)
          acc[mi][ni] = __builtin_amdgcn_mfma_f32_16x16x32_f16(af[mi], bf[ni], acc[mi][ni], 0, 0, 0);
    }
    __syncthreads();
  }
  const float inv = 1.f / 256.f;
#pragma unroll
  for (int mi = 0; mi < 4; ++mi) {
#pragma unroll
    for (int reg = 0; reg < 4; ++reg) {
      const int r = m_blk + wm * 64 + mi * 16 + quad * 4 + reg;
      if (r < M) {
#pragma unroll
        for (int ni = 0; ni < 4; ++ni) {
          C[(size_t)r * Ntot + n_blk + wn * 64 + ni * 16 + row16] =
              (_Float16)(acc[mi][ni][reg] * inv);
        }
      }
    }
  }
}

// ---- conv1 attention: one block per dst node, f16 gathers, 8 ch/thread ----
// xlrp rows (f16): [0:W]=xl, [W:2W]=xr. h1 written fp32, row stride 1024.
__global__ __launch_bounds__(128) void conv1_attn(const _Float16* __restrict__ xlrp,
                                                  const int* __restrict__ row_ptr,
                                                  const int* __restrict__ col,
                                                  const float* __restrict__ att,
                                                  const float* __restrict__ bias,
                                                  float* __restrict__ h1, int W) {
  const int i = blockIdx.x;
  const int tid = threadIdx.x;
  const int nt = blockDim.x;  // W/8
  const int f = tid * 8;      // 8 channels/thread; head group = 16 threads
  __shared__ int s_col[128];
  float a[8], xr[8], acc[8];
  {
    const float4 a0 = *(const float4*)(att + f);
    const float4 a1 = *(const float4*)(att + f + 4);
    a[0] = a0.x; a[1] = a0.y; a[2] = a0.z; a[3] = a0.w;
    a[4] = a1.x; a[5] = a1.y; a[6] = a1.z; a[7] = a1.w;
    const half8 x8 = *(const half8*)(xlrp + (size_t)i * (2 * W) + W + f);
#pragma unroll
    for (int c = 0; c < 8; ++c) { xr[c] = (float)x8[c]; acc[c] = 0.f; }
  }
  float m = -3.0e38f, l = 0.f;
  const int kb = row_ptr[i];
  const int ke = row_ptr[i + 1];
  for (int base = kb; base < ke; base += nt) {
    const int cnt = min(nt, ke - base);
    if (tid < cnt) s_col[tid] = col[base + tid];
    __syncthreads();
    half8 xc = *(const half8*)(xlrp + (size_t)s_col[0] * (2 * W) + f);
    for (int q = 0; q < cnt; ++q) {
      half8 xn = xc;
      if (q + 1 < cnt) xn = *(const half8*)(xlrp + (size_t)s_col[q + 1] * (2 * W) + f);
      float xv[8];
      float s = 0.f;
#pragma unroll
      for (int c = 0; c < 8; ++c) {
        xv[c] = (float)xc[c];
        const float t = xv[c] + xr[c];
        s += a[c] * (t > 0.f ? t : 0.2f * t);
      }
      // reduce across the 16-lane head group
      s += __shfl_xor(s, 8);
      s += __shfl_xor(s, 4);
      s += __shfl_xor(s, 2);
      s += __shfl_xor(s, 1);
      if (s <= m) {  // common case: running max unchanged, no rescale
        const float p = __expf(s - m);
        l += p;
#pragma unroll
        for (int c = 0; c < 8; ++c) acc[c] += p * xv[c];
      } else {
        const float sc = __expf(m - s);
        m = s;
        l = l * sc + 1.f;
#pragma unroll
        for (int c = 0; c < 8; ++c) acc[c] = acc[c] * sc + xv[c];
      }
      xc = xn;
    }
    __syncthreads();
  }
  const float inv = 1.f / (l + 1e-16f);
  float o[8];
#pragma unroll
  for (int c = 0; c < 8; ++c) o[c] = acc[c] * inv + bias[f + c];
  float* outp = h1 + (size_t)i * 1024 + f;
  *(float4*)(outp) = make_float4(o[0], o[1], o[2], o[3]);
  *(float4*)(outp + 4) = make_float4(o[4], o[5], o[6], o[7]);
}

// ---------------- BN1 stats ----------------
__global__ __launch_bounds__(256) void bn1_stats(const float* __restrict__ h1,
                                                 float* __restrict__ bsum,
                                                 float* __restrict__ bsq, int N) {
  const int fidx = blockIdx.x * 256 + threadIdx.x;
  const int chunk = (N + 63) / 64;
  const int r0 = blockIdx.y * chunk;
  const int r1 = min(N, r0 + chunk);
  float s = 0.f, q = 0.f;
  for (int r = r0; r < r1; ++r) {
    const float v = h1[(size_t)r * 1024 + fidx];
    s += v;
    q += v * v;
  }
  atomicAdd(&bsum[fidx], s);
  atomicAdd(&bsq[fidx], q);
}

// ---------------- BN1 apply + lrelu + conv2 projections ----------------
__global__ __launch_bounds__(256) void bn1_proj(const float* __restrict__ h1,
                                                const float* __restrict__ bsum,
                                                const float* __restrict__ bsq,
                                                const float* __restrict__ g1,
                                                const float* __restrict__ be1,
                                                const float* __restrict__ w2l,
                                                const float* __restrict__ w2r,
                                                float* __restrict__ xl2,
                                                float* __restrict__ xr2, int N) {
  const int i = blockIdx.x;
  const int tid = threadIdx.x;
  const int f = tid * 4;
  const float4 h4 = *(const float4*)(h1 + (size_t)i * 1024 + f);
  const float4 s4 = *(const float4*)(bsum + f);
  const float4 q4 = *(const float4*)(bsq + f);
  const float4 g4 = *(const float4*)(g1 + f);
  const float4 b4 = *(const float4*)(be1 + f);
  const float4 wl = *(const float4*)(w2l + f);
  const float4 wr = *(const float4*)(w2r + f);
  const float invN = 1.f / (float)N;
  float pl = 0.f, pr = 0.f;
  {
    float mu, var, rs, v;
    mu = s4.x * invN; var = q4.x * invN - mu * mu; rs = 1.f / sqrtf(var + 1e-5f);
    v = lrelu((h4.x - mu) * rs * g4.x + b4.x, 0.01f); pl += v * wl.x; pr += v * wr.x;
    mu = s4.y * invN; var = q4.y * invN - mu * mu; rs = 1.f / sqrtf(var + 1e-5f);
    v = lrelu((h4.y - mu) * rs * g4.y + b4.y, 0.01f); pl += v * wl.y; pr += v * wr.y;
    mu = s4.z * invN; var = q4.z * invN - mu * mu; rs = 1.f / sqrtf(var + 1e-5f);
    v = lrelu((h4.z - mu) * rs * g4.z + b4.z, 0.01f); pl += v * wl.z; pr += v * wr.z;
    mu = s4.w * invN; var = q4.w * invN - mu * mu; rs = 1.f / sqrtf(var + 1e-5f);
    v = lrelu((h4.w - mu) * rs * g4.w + b4.w, 0.01f); pl += v * wl.w; pr += v * wr.w;
  }
#pragma unroll
  for (int off = 32; off; off >>= 1) {
    pl += __shfl_down(pl, off);
    pr += __shfl_down(pr, off);
  }
  __shared__ float sp[8];
  if ((tid & 63) == 0) {
    sp[tid >> 6] = pl;
    sp[4 + (tid >> 6)] = pr;
  }
  __syncthreads();
  if (tid == 0) {
    xl2[i] = sp[0] + sp[1] + sp[2] + sp[3];
    xr2[i] = sp[4] + sp[5] + sp[6] + sp[7];
  }
}

// ---------------- conv2 attention: one thread per node ----------------
__global__ void conv2_attn(const float* __restrict__ xl2, const float* __restrict__ xr2,
                           const int* __restrict__ row_ptr, const int* __restrict__ col,
                           const float* __restrict__ att2, const float* __restrict__ b2,
                           float* __restrict__ out2, int N) {
  const int i = blockIdx.x * blockDim.x + threadIdx.x;
  if (i >= N) return;
  const float a = att2[0];
  const float xr = xr2[i];
  float m = -3.0e38f, l = 0.f, acc = 0.f;
  const int kb = row_ptr[i];
  const int ke = row_ptr[i + 1];
  for (int k = kb; k < ke; ++k) {
    const float xv = xl2[col[k]];
    const float s = a * lrelu(xv + xr, 0.2f);
    const float mn = fmaxf(m, s);
    const float sc = __expf(m - mn);
    const float p = __expf(s - mn);
    l = l * sc + p;
    acc = acc * sc + p * xv;
    m = mn;
  }
  out2[i] = acc / (l + 1e-16f) + b2[0];
}

// ---------------- BN2 stats ----------------
__global__ void bn2_stats(const float* __restrict__ out2, float* __restrict__ bn2acc, int N) {
  const int i = blockIdx.x * blockDim.x + threadIdx.x;
  const float v = (i < N) ? out2[i] : 0.f;
  float s = v, q = v * v;
#pragma unroll
  for (int off = 32; off; off >>= 1) {
    s += __shfl_down(s, off);
    q += __shfl_down(q, off);
  }
  if ((threadIdx.x & 63) == 0) {
    atomicAdd(&bn2acc[0], s);
    atomicAdd(&bn2acc[1], q);
  }
}

// ---------------- BN2 apply + lrelu + graph mean pool ----------------
__global__ void bn2_pool(const float* __restrict__ out2, const float* __restrict__ bn2acc,
                         const float* __restrict__ g2, const float* __restrict__ be2,
                         const int* __restrict__ batch,
                         float* __restrict__ pool_sum, float* __restrict__ pool_cnt, int N) {
  const int i = blockIdx.x * blockDim.x + threadIdx.x;
  if (i >= N) return;
  const float invN = 1.f / (float)N;
  const float mu = bn2acc[0] * invN;
  const float var = bn2acc[1] * invN - mu * mu;
  const float rs = 1.f / sqrtf(var + 1e-5f);
  const float v = lrelu((out2[i] - mu) * rs * g2[0] + be2[0], 0.01f);
  const int g = batch[i];
  atomicAdd(&pool_sum[g], v);
  atomicAdd(&pool_cnt[g], 1.0f);
}

// ---------------- MLP head ----------------
__global__ void head_mlp(const float* __restrict__ pool_sum, const float* __restrict__ pool_cnt,
                         const float* __restrict__ lw1, const float* __restrict__ lb1,
                         const float* __restrict__ lw2, const float* __restrict__ lb2,
                         float* __restrict__ out) {
  const int g = threadIdx.x;
  if (g >= 64) return;
  const float p = pool_sum[g] / fmaxf(pool_cnt[g], 1.f);
  float acc = 0.f;
  for (int d = 0; d < 128; ++d) {
    float t = p * lw1[d] + lb1[d];
    t = lrelu(t, 0.01f);
    acc += t * lw2[d];
  }
  out[g] = acc + lb2[0];
}

extern "C" void kernel_launch(void* const* d_in, const int* in_sizes, int n_in,
                              void* d_out, int out_size, void* d_ws, size_t ws_size,
                              hipStream_t stream) {
  const float* x = (const float*)d_in[0];
  const int* ei = (const int*)d_in[1];
  const int* batch = (const int*)d_in[2];
  const float* w1_l = (const float*)d_in[3];
  const float* w1_r = (const float*)d_in[4];
  const float* att1 = (const float*)d_in[5];
  const float* b1 = (const float*)d_in[6];
  const float* g1 = (const float*)d_in[7];
  const float* be1 = (const float*)d_in[8];
  const float* w2_l = (const float*)d_in[9];
  const float* w2_r = (const float*)d_in[10];
  const float* att2 = (const float*)d_in[11];
  const float* b2 = (const float*)d_in[12];
  const float* g2 = (const float*)d_in[13];
  const float* be2 = (const float*)d_in[14];
  const float* lw1 = (const float*)d_in[15];
  const float* lb1 = (const float*)d_in[16];
  const float* lw2 = (const float*)d_in[17];
  const float* lb2 = (const float*)d_in[18];

  const int N = in_sizes[2];
  const int E = in_sizes[1] / 2;
  const int ET = E + N;

  const size_t AL = 255;
  auto al = [&](size_t b) { return (b + AL) & ~AL; };
  const size_t zbytes = (size_t)N * 4 + 4096 + 4096 + 16 + 256 + 256;
  const size_t fixedNoXlr = al((size_t)N * 4096)     // h1 (fp32)
                          + 3 * al((size_t)N * 4)    // xl2, xr2, out2
                          + al((size_t)(N + 1) * 4)  // row_ptr
                          + al((size_t)ET * 4)       // col
                          + al((size_t)N * 4)        // cursor
                          + al(zbytes);
  const size_t a2b = al((size_t)N * 512 * 2);
  int P = 1;
  while (P < 8) {
    const size_t xlrb = al((size_t)N * (4096 / P));  // f16 now
    const size_t b3b = al((size_t)(2 * (1024 / P)) * 768 * 2);
    const size_t extra = (P == 1) ? 0 : (a2b + b3b);
    if (fixedNoXlr + xlrb + extra <= ws_size) break;
    P <<= 1;
  }
  const int W = 1024 / P;

  char* ws = (char*)d_ws;
  size_t off = 0;
  auto alloc = [&](size_t b) { size_t p = off; off += al(b); return p; };
  float* h1 = (float*)(ws + alloc((size_t)N * 4096));
  _Float16* xlrp = (_Float16*)(ws + alloc((size_t)N * (4096 / P)));
  float* xl2 = (float*)(ws + alloc((size_t)N * 4));
  float* xr2 = (float*)(ws + alloc((size_t)N * 4));
  float* out2 = (float*)(ws + alloc((size_t)N * 4));
  int* row_ptr = (int*)(ws + alloc((size_t)(N + 1) * 4));
  int* colb = (int*)(ws + alloc((size_t)ET * 4));
  int* cursor = (int*)(ws + alloc((size_t)N * 4));
  char* zbase = ws + alloc(zbytes);
  int* counts = (int*)zbase;
  float* bn1_sum = (float*)(zbase + (size_t)N * 4);
  float* bn1_sq = (float*)(zbase + (size_t)N * 4 + 4096);
  float* bn2acc = (float*)(zbase + (size_t)N * 4 + 8192);
  float* pool_sum = (float*)(zbase + (size_t)N * 4 + 8192 + 16);
  float* pool_cnt = (float*)(zbase + (size_t)N * 4 + 8192 + 16 + 256);

  _Float16 *A2, *B3;
  if (P == 1) {  // h1 is dead until conv1_attn -> alias A2/B3 into it
    A2 = (_Float16*)h1;
    B3 = (_Float16*)((char*)h1 + a2b);
  } else {
    A2 = (_Float16*)(ws + alloc((size_t)N * 512 * 2));
    B3 = (_Float16*)(ws + alloc((size_t)(2 * W) * 768 * 2));
  }

  const int zn = (int)(zbytes / 4);
  zero_ints<<<(zn + 255) / 256, 256, 0, stream>>>((int*)zbase, zn);

  edge_hist<<<(ET + 255) / 256, 256, 0, stream>>>(ei, E, N, counts);
  scan_counts<<<1, 1024, 0, stream>>>(counts, row_ptr, cursor, N);
  edge_scatter<<<(ET + 255) / 256, 256, 0, stream>>>(ei, E, N, cursor, colb);

  convert_x<<<(N * 64 + 255) / 256, 256, 0, stream>>>(x, A2, N);
  for (int p = 0; p < P; ++p) {
    convert_w<<<dim3((2 * W + 255) / 256, 256), 256, 0, stream>>>(w1_l, w1_r, B3, p * W, W);
    gemm_mfma<<<dim3(2 * W / 128, (N + 127) / 128), 256, 0, stream>>>(A2, B3, xlrp, N, 2 * W);
    conv1_attn<<<N, W / 8, 0, stream>>>(xlrp, row_ptr, colb,
                                        att1 + p * W, b1 + p * W, h1 + p * W, W);
  }

  bn1_stats<<<dim3(4, 64), 256, 0, stream>>>(h1, bn1_sum, bn1_sq, N);
  bn1_proj<<<N, 256, 0, stream>>>(h1, bn1_sum, bn1_sq, g1, be1, w2_l, w2_r, xl2, xr2, N);
  conv2_attn<<<(N + 255) / 256, 256, 0, stream>>>(xl2, xr2, row_ptr, colb, att2, b2, out2, N);
  bn2_stats<<<(N + 255) / 256, 256, 0, stream>>>(out2, bn2acc, N);
  bn2_pool<<<(N + 255) / 256, 256, 0, stream>>>(out2, bn2acc, g2, be2, batch, pool_sum, pool_cnt, N);
  head_mlp<<<1, 64, 0, stream>>>(pool_sum, pool_cnt, lw1, lb1, lw2, lb2, (float*)d_out);
}

// Round 5
// 513.148 us; speedup vs baseline: 1.8068x; 1.2483x over previous
//
#include <hip/hip_runtime.h>
#include <hip/hip_bf16.h>

// GATv2 x2 + BN + pool + MLP for MI355X. Round 5: bn2_pool atomics fixed —
// sorted batch made all 64 lanes of each wave hit the same pool_sum[g]
// address with serialized float atomics (130 us, VALUBusy 0.02%). Now:
// LDS 64-bin pre-reduction per block, then <=64 global atomics per block.

__device__ __forceinline__ float lrelu(float x, float s) { return x > 0.f ? x : s * x; }

typedef _Float16 half8 __attribute__((ext_vector_type(8)));
typedef _Float16 half4v __attribute__((ext_vector_type(4)));
typedef float f32x4 __attribute__((ext_vector_type(4)));

#define GLOBAL_AS __attribute__((address_space(1)))
#define LDS_AS __attribute__((address_space(3)))

__device__ __forceinline__ void async_copy16(const void* g, void* l) {
  __builtin_amdgcn_global_load_lds((const GLOBAL_AS unsigned int*)g,
                                   (LDS_AS unsigned int*)l, 16, 0, 0);
}

__global__ void zero_ints(int* __restrict__ p, int n) {
  const int t = blockIdx.x * blockDim.x + threadIdx.x;
  if (t < n) p[t] = 0;
}

// ---------------- CSR build (by dst, self-loops appended) ----------------
__global__ void edge_hist(const int* __restrict__ ei, int E, int N,
                          int* __restrict__ counts) {
  const int t = blockIdx.x * blockDim.x + threadIdx.x;
  if (t >= E + N) return;
  const int dst = (t < E) ? ei[E + t] : (t - E);
  atomicAdd(&counts[dst], 1);
}

__global__ __launch_bounds__(1024) void scan_counts(const int* __restrict__ counts,
                                                    int* __restrict__ row_ptr,
                                                    int* __restrict__ cursor, int N) {
  __shared__ int sdata[1024];
  const int t = threadIdx.x;
  const int chunk = (N + 1023) / 1024;
  const int s0 = t * chunk;
  const int s1 = min(N, s0 + chunk);
  int lsum = 0;
  for (int i = s0; i < s1; ++i) lsum += counts[i];
  sdata[t] = lsum;
  __syncthreads();
  for (int off = 1; off < 1024; off <<= 1) {
    int v = 0;
    if (t >= off) v = sdata[t - off];
    __syncthreads();
    sdata[t] += v;
    __syncthreads();
  }
  int run = sdata[t] - lsum;
  for (int i = s0; i < s1; ++i) {
    row_ptr[i] = run;
    cursor[i] = run;
    run += counts[i];
  }
  if (s0 < N && s1 == N) row_ptr[N] = run;
}

__global__ void edge_scatter(const int* __restrict__ ei, int E, int N,
                             int* __restrict__ cursor, int* __restrict__ col) {
  const int t = blockIdx.x * blockDim.x + threadIdx.x;
  if (t >= E + N) return;
  const int dst = (t < E) ? ei[E + t] : (t - E);
  const int src = (t < E) ? ei[t] : (t - E);
  const int pos = atomicAdd(&cursor[dst], 1);
  col[pos] = src;
}

// ---------------- split-f16 conversions (scale x16) ----------------
__global__ void convert_x(const float* __restrict__ x, _Float16* __restrict__ A2, int M) {
  const int t = blockIdx.x * blockDim.x + threadIdx.x;
  if (t >= M * 64) return;
  const int m = t >> 6;
  const int k4 = (t & 63) * 4;
  const float4 v = *(const float4*)(x + (size_t)m * 256 + k4);
  const float sx = 16.f;
  _Float16 h0 = (_Float16)(v.x * sx), h1 = (_Float16)(v.y * sx),
           h2 = (_Float16)(v.z * sx), h3 = (_Float16)(v.w * sx);
  _Float16 l0 = (_Float16)(v.x * sx - (float)h0), l1 = (_Float16)(v.y * sx - (float)h1),
           l2 = (_Float16)(v.z * sx - (float)h2), l3 = (_Float16)(v.w * sx - (float)h3);
  _Float16* rowp = A2 + (size_t)m * 512;
  *(half4v*)(rowp + k4) = (half4v){h0, h1, h2, h3};
  *(half4v*)(rowp + 256 + k4) = (half4v){l0, l1, l2, l3};
}

__global__ void convert_w(const float* __restrict__ wl, const float* __restrict__ wr,
                          _Float16* __restrict__ B3, int colOff, int W) {
  const int k = blockIdx.y;  // 0..255
  const int n = blockIdx.x * blockDim.x + threadIdx.x;
  if (n >= 2 * W) return;
  const float v = 16.f * ((n < W) ? wl[k * 1024 + colOff + n]
                                  : wr[k * 1024 + colOff + (n - W)]);
  const _Float16 h = (_Float16)v;
  const _Float16 l = (_Float16)(v - (float)h);
  _Float16* rowp = B3 + (size_t)n * 768;
  rowp[k] = h;
  rowp[256 + k] = h;
  rowp[512 + k] = l;
}

// ------- MFMA GEMM: xlr[M x Ntot] (f16) = ((A2 ext) @ B3^T) / 256 ----------
__global__ __launch_bounds__(256) void gemm_mfma(const _Float16* __restrict__ A2,
                                                 const _Float16* __restrict__ B3,
                                                 _Float16* __restrict__ C,
                                                 int M, int Ntot) {
  __shared__ __align__(16) _Float16 As[128 * 64];
  __shared__ __align__(16) _Float16 Bs[128 * 64];
  const int tid = threadIdx.x;
  const int lane = tid & 63;
  const int wv = tid >> 6;
  const int wm = wv & 1, wn = wv >> 1;
  const int m_blk = blockIdx.y * 128;
  const int n_blk = blockIdx.x * 128;
  const int row16 = lane & 15, quad = lane >> 4;
  f32x4 acc[4][4] = {};

  for (int kt = 0; kt < 12; ++kt) {
    const int kg = kt * 64;
    const int ka = (kg < 512) ? kg : kg - 512;  // hi cols reused for hi*lo term
#pragma unroll
    for (int j = 0; j < 4; ++j) {
      const int ci = j * 256 + tid;
      const int row = ci >> 3;
      const int c = ci & 7;
      const int gc = c ^ (row & 7);
      _Float16* ldsA = &As[(j * 256 + wv * 64) * 8];
      _Float16* ldsB = &Bs[(j * 256 + wv * 64) * 8];
      const int growA = min(m_blk + row, M - 1);
      async_copy16(A2 + (size_t)growA * 512 + ka + gc * 8, ldsA);
      async_copy16(B3 + (size_t)(n_blk + row) * 768 + kg + gc * 8, ldsB);
    }
    __syncthreads();
#pragma unroll
    for (int ks = 0; ks < 2; ++ks) {
      half8 af[4], bf[4];
#pragma unroll
      for (int mi = 0; mi < 4; ++mi) {
        const int r = wm * 64 + mi * 16 + row16;
        const int cl = (ks * 4 + quad) ^ (r & 7);
        af[mi] = *(const half8*)&As[r * 64 + cl * 8];
      }
#pragma unroll
      for (int ni = 0; ni < 4; ++ni) {
        const int r = wn * 64 + ni * 16 + row16;
        const int cl = (ks * 4 + quad) ^ (r & 7);
        bf[ni] = *(const half8*)&Bs[r * 64 + cl * 8];
      }
#pragma unroll
      for (int mi = 0; mi < 4; ++mi)
#pragma unroll
        for (int ni = 0; ni < 4; ++ni)
          acc[mi][ni] = __builtin_amdgcn_mfma_f32_16x16x32_f16(af[mi], bf[ni], acc[mi][ni], 0, 0, 0);
    }
    __syncthreads();
  }
  const float inv = 1.f / 256.f;
#pragma unroll
  for (int mi = 0; mi < 4; ++mi) {
#pragma unroll
    for (int reg = 0; reg < 4; ++reg) {
      const int r = m_blk + wm * 64 + mi * 16 + quad * 4 + reg;
      if (r < M) {
#pragma unroll
        for (int ni = 0; ni < 4; ++ni) {
          C[(size_t)r * Ntot + n_blk + wn * 64 + ni * 16 + row16] =
              (_Float16)(acc[mi][ni][reg] * inv);
        }
      }
    }
  }
}

// ---- conv1 attention: one block per dst node, f16 gathers, 8 ch/thread ----
__global__ __launch_bounds__(128) void conv1_attn(const _Float16* __restrict__ xlrp,
                                                  const int* __restrict__ row_ptr,
                                                  const int* __restrict__ col,
                                                  const float* __restrict__ att,
                                                  const float* __restrict__ bias,
                                                  float* __restrict__ h1, int W) {
  const int i = blockIdx.x;
  const int tid = threadIdx.x;
  const int nt = blockDim.x;  // W/8
  const int f = tid * 8;      // 8 channels/thread; head group = 16 threads
  __shared__ int s_col[128];
  float a[8], xr[8], acc[8];
  {
    const float4 a0 = *(const float4*)(att + f);
    const float4 a1 = *(const float4*)(att + f + 4);
    a[0] = a0.x; a[1] = a0.y; a[2] = a0.z; a[3] = a0.w;
    a[4] = a1.x; a[5] = a1.y; a[6] = a1.z; a[7] = a1.w;
    const half8 x8 = *(const half8*)(xlrp + (size_t)i * (2 * W) + W + f);
#pragma unroll
    for (int c = 0; c < 8; ++c) { xr[c] = (float)x8[c]; acc[c] = 0.f; }
  }
  float m = -3.0e38f, l = 0.f;
  const int kb = row_ptr[i];
  const int ke = row_ptr[i + 1];
  for (int base = kb; base < ke; base += nt) {
    const int cnt = min(nt, ke - base);
    if (tid < cnt) s_col[tid] = col[base + tid];
    __syncthreads();
    half8 xc = *(const half8*)(xlrp + (size_t)s_col[0] * (2 * W) + f);
    for (int q = 0; q < cnt; ++q) {
      half8 xn = xc;
      if (q + 1 < cnt) xn = *(const half8*)(xlrp + (size_t)s_col[q + 1] * (2 * W) + f);
      float xv[8];
      float s = 0.f;
#pragma unroll
      for (int c = 0; c < 8; ++c) {
        xv[c] = (float)xc[c];
        const float t = xv[c] + xr[c];
        s += a[c] * (t > 0.f ? t : 0.2f * t);
      }
      s += __shfl_xor(s, 8);
      s += __shfl_xor(s, 4);
      s += __shfl_xor(s, 2);
      s += __shfl_xor(s, 1);
      if (s <= m) {
        const float p = __expf(s - m);
        l += p;
#pragma unroll
        for (int c = 0; c < 8; ++c) acc[c] += p * xv[c];
      } else {
        const float sc = __expf(m - s);
        m = s;
        l = l * sc + 1.f;
#pragma unroll
        for (int c = 0; c < 8; ++c) acc[c] = acc[c] * sc + xv[c];
      }
      xc = xn;
    }
    __syncthreads();
  }
  const float inv = 1.f / (l + 1e-16f);
  float o[8];
#pragma unroll
  for (int c = 0; c < 8; ++c) o[c] = acc[c] * inv + bias[f + c];
  float* outp = h1 + (size_t)i * 1024 + f;
  *(float4*)(outp) = make_float4(o[0], o[1], o[2], o[3]);
  *(float4*)(outp + 4) = make_float4(o[4], o[5], o[6], o[7]);
}

// ---------------- BN1 stats ----------------
__global__ __launch_bounds__(256) void bn1_stats(const float* __restrict__ h1,
                                                 float* __restrict__ bsum,
                                                 float* __restrict__ bsq, int N) {
  const int fidx = blockIdx.x * 256 + threadIdx.x;
  const int chunk = (N + 63) / 64;
  const int r0 = blockIdx.y * chunk;
  const int r1 = min(N, r0 + chunk);
  float s = 0.f, q = 0.f;
  for (int r = r0; r < r1; ++r) {
    const float v = h1[(size_t)r * 1024 + fidx];
    s += v;
    q += v * v;
  }
  atomicAdd(&bsum[fidx], s);
  atomicAdd(&bsq[fidx], q);
}

// ---------------- BN1 apply + lrelu + conv2 projections ----------------
__global__ __launch_bounds__(256) void bn1_proj(const float* __restrict__ h1,
                                                const float* __restrict__ bsum,
                                                const float* __restrict__ bsq,
                                                const float* __restrict__ g1,
                                                const float* __restrict__ be1,
                                                const float* __restrict__ w2l,
                                                const float* __restrict__ w2r,
                                                float* __restrict__ xl2,
                                                float* __restrict__ xr2, int N) {
  const int i = blockIdx.x;
  const int tid = threadIdx.x;
  const int f = tid * 4;
  const float4 h4 = *(const float4*)(h1 + (size_t)i * 1024 + f);
  const float4 s4 = *(const float4*)(bsum + f);
  const float4 q4 = *(const float4*)(bsq + f);
  const float4 g4 = *(const float4*)(g1 + f);
  const float4 b4 = *(const float4*)(be1 + f);
  const float4 wl = *(const float4*)(w2l + f);
  const float4 wr = *(const float4*)(w2r + f);
  const float invN = 1.f / (float)N;
  float pl = 0.f, pr = 0.f;
  {
    float mu, var, rs, v;
    mu = s4.x * invN; var = q4.x * invN - mu * mu; rs = 1.f / sqrtf(var + 1e-5f);
    v = lrelu((h4.x - mu) * rs * g4.x + b4.x, 0.01f); pl += v * wl.x; pr += v * wr.x;
    mu = s4.y * invN; var = q4.y * invN - mu * mu; rs = 1.f / sqrtf(var + 1e-5f);
    v = lrelu((h4.y - mu) * rs * g4.y + b4.y, 0.01f); pl += v * wl.y; pr += v * wr.y;
    mu = s4.z * invN; var = q4.z * invN - mu * mu; rs = 1.f / sqrtf(var + 1e-5f);
    v = lrelu((h4.z - mu) * rs * g4.z + b4.z, 0.01f); pl += v * wl.z; pr += v * wr.z;
    mu = s4.w * invN; var = q4.w * invN - mu * mu; rs = 1.f / sqrtf(var + 1e-5f);
    v = lrelu((h4.w - mu) * rs * g4.w + b4.w, 0.01f); pl += v * wl.w; pr += v * wr.w;
  }
#pragma unroll
  for (int off = 32; off; off >>= 1) {
    pl += __shfl_down(pl, off);
    pr += __shfl_down(pr, off);
  }
  __shared__ float sp[8];
  if ((tid & 63) == 0) {
    sp[tid >> 6] = pl;
    sp[4 + (tid >> 6)] = pr;
  }
  __syncthreads();
  if (tid == 0) {
    xl2[i] = sp[0] + sp[1] + sp[2] + sp[3];
    xr2[i] = sp[4] + sp[5] + sp[6] + sp[7];
  }
}

// ---------------- conv2 attention: one thread per node ----------------
__global__ void conv2_attn(const float* __restrict__ xl2, const float* __restrict__ xr2,
                           const int* __restrict__ row_ptr, const int* __restrict__ col,
                           const float* __restrict__ att2, const float* __restrict__ b2,
                           float* __restrict__ out2, int N) {
  const int i = blockIdx.x * blockDim.x + threadIdx.x;
  if (i >= N) return;
  const float a = att2[0];
  const float xr = xr2[i];
  float m = -3.0e38f, l = 0.f, acc = 0.f;
  const int kb = row_ptr[i];
  const int ke = row_ptr[i + 1];
  for (int k = kb; k < ke; ++k) {
    const float xv = xl2[col[k]];
    const float s = a * lrelu(xv + xr, 0.2f);
    const float mn = fmaxf(m, s);
    const float sc = __expf(m - mn);
    const float p = __expf(s - mn);
    l = l * sc + p;
    acc = acc * sc + p * xv;
    m = mn;
  }
  out2[i] = acc / (l + 1e-16f) + b2[0];
}

// ---------------- BN2 stats ----------------
__global__ void bn2_stats(const float* __restrict__ out2, float* __restrict__ bn2acc, int N) {
  const int i = blockIdx.x * blockDim.x + threadIdx.x;
  const float v = (i < N) ? out2[i] : 0.f;
  float s = v, q = v * v;
#pragma unroll
  for (int off = 32; off; off >>= 1) {
    s += __shfl_down(s, off);
    q += __shfl_down(q, off);
  }
  if ((threadIdx.x & 63) == 0) {
    atomicAdd(&bn2acc[0], s);
    atomicAdd(&bn2acc[1], q);
  }
}

// -------- BN2 apply + lrelu + graph mean pool (LDS pre-reduction) ---------
// Sorted batch => a wave's lanes share g; global same-address float atomics
// serialized at L2 cost 130us. LDS 64-bin accumulate per block, then <=64
// global atomics per block (only bins this block touched).
__global__ __launch_bounds__(256) void bn2_pool(const float* __restrict__ out2,
                                                const float* __restrict__ bn2acc,
                                                const float* __restrict__ g2,
                                                const float* __restrict__ be2,
                                                const int* __restrict__ batch,
                                                float* __restrict__ pool_sum,
                                                float* __restrict__ pool_cnt, int N) {
  __shared__ float ls[64];
  __shared__ float lc[64];
  const int tid = threadIdx.x;
  if (tid < 64) { ls[tid] = 0.f; lc[tid] = 0.f; }
  __syncthreads();
  const int i = blockIdx.x * blockDim.x + tid;
  if (i < N) {
    const float invN = 1.f / (float)N;
    const float mu = bn2acc[0] * invN;
    const float var = bn2acc[1] * invN - mu * mu;
    const float rs = 1.f / sqrtf(var + 1e-5f);
    const float v = lrelu((out2[i] - mu) * rs * g2[0] + be2[0], 0.01f);
    const int g = batch[i];
    atomicAdd(&ls[g], v);   // LDS atomic: cheap even when serialized
    atomicAdd(&lc[g], 1.f);
  }
  __syncthreads();
  if (tid < 64 && lc[tid] != 0.f) {
    atomicAdd(&pool_sum[tid], ls[tid]);
    atomicAdd(&pool_cnt[tid], lc[tid]);
  }
}

// ---------------- MLP head ----------------
__global__ void head_mlp(const float* __restrict__ pool_sum, const float* __restrict__ pool_cnt,
                         const float* __restrict__ lw1, const float* __restrict__ lb1,
                         const float* __restrict__ lw2, const float* __restrict__ lb2,
                         float* __restrict__ out) {
  const int g = threadIdx.x;
  if (g >= 64) return;
  const float p = pool_sum[g] / fmaxf(pool_cnt[g], 1.f);
  float acc = 0.f;
  for (int d = 0; d < 128; ++d) {
    float t = p * lw1[d] + lb1[d];
    t = lrelu(t, 0.01f);
    acc += t * lw2[d];
  }
  out[g] = acc + lb2[0];
}

extern "C" void kernel_launch(void* const* d_in, const int* in_sizes, int n_in,
                              void* d_out, int out_size, void* d_ws, size_t ws_size,
                              hipStream_t stream) {
  const float* x = (const float*)d_in[0];
  const int* ei = (const int*)d_in[1];
  const int* batch = (const int*)d_in[2];
  const float* w1_l = (const float*)d_in[3];
  const float* w1_r = (const float*)d_in[4];
  const float* att1 = (const float*)d_in[5];
  const float* b1 = (const float*)d_in[6];
  const float* g1 = (const float*)d_in[7];
  const float* be1 = (const float*)d_in[8];
  const float* w2_l = (const float*)d_in[9];
  const float* w2_r = (const float*)d_in[10];
  const float* att2 = (const float*)d_in[11];
  const float* b2 = (const float*)d_in[12];
  const float* g2 = (const float*)d_in[13];
  const float* be2 = (const float*)d_in[14];
  const float* lw1 = (const float*)d_in[15];
  const float* lb1 = (const float*)d_in[16];
  const float* lw2 = (const float*)d_in[17];
  const float* lb2 = (const float*)d_in[18];

  const int N = in_sizes[2];
  const int E = in_sizes[1] / 2;
  const int ET = E + N;

  const size_t AL = 255;
  auto al = [&](size_t b) { return (b + AL) & ~AL; };
  const size_t zbytes = (size_t)N * 4 + 4096 + 4096 + 16 + 256 + 256;
  const size_t fixedNoXlr = al((size_t)N * 4096)     // h1 (fp32)
                          + 3 * al((size_t)N * 4)    // xl2, xr2, out2
                          + al((size_t)(N + 1) * 4)  // row_ptr
                          + al((size_t)ET * 4)       // col
                          + al((size_t)N * 4)        // cursor
                          + al(zbytes);
  const size_t a2b = al((size_t)N * 512 * 2);
  int P = 1;
  while (P < 8) {
    const size_t xlrb = al((size_t)N * (4096 / P));  // f16
    const size_t b3b = al((size_t)(2 * (1024 / P)) * 768 * 2);
    const size_t extra = (P == 1) ? 0 : (a2b + b3b);
    if (fixedNoXlr + xlrb + extra <= ws_size) break;
    P <<= 1;
  }
  const int W = 1024 / P;

  char* ws = (char*)d_ws;
  size_t off = 0;
  auto alloc = [&](size_t b) { size_t p = off; off += al(b); return p; };
  float* h1 = (float*)(ws + alloc((size_t)N * 4096));
  _Float16* xlrp = (_Float16*)(ws + alloc((size_t)N * (4096 / P)));
  float* xl2 = (float*)(ws + alloc((size_t)N * 4));
  float* xr2 = (float*)(ws + alloc((size_t)N * 4));
  float* out2 = (float*)(ws + alloc((size_t)N * 4));
  int* row_ptr = (int*)(ws + alloc((size_t)(N + 1) * 4));
  int* colb = (int*)(ws + alloc((size_t)ET * 4));
  int* cursor = (int*)(ws + alloc((size_t)N * 4));
  char* zbase = ws + alloc(zbytes);
  int* counts = (int*)zbase;
  float* bn1_sum = (float*)(zbase + (size_t)N * 4);
  float* bn1_sq = (float*)(zbase + (size_t)N * 4 + 4096);
  float* bn2acc = (float*)(zbase + (size_t)N * 4 + 8192);
  float* pool_sum = (float*)(zbase + (size_t)N * 4 + 8192 + 16);
  float* pool_cnt = (float*)(zbase + (size_t)N * 4 + 8192 + 16 + 256);

  _Float16 *A2, *B3;
  if (P == 1) {  // h1 is dead until conv1_attn -> alias A2/B3 into it
    A2 = (_Float16*)h1;
    B3 = (_Float16*)((char*)h1 + a2b);
  } else {
    A2 = (_Float16*)(ws + alloc((size_t)N * 512 * 2));
    B3 = (_Float16*)(ws + alloc((size_t)(2 * W) * 768 * 2));
  }

  const int zn = (int)(zbytes / 4);
  zero_ints<<<(zn + 255) / 256, 256, 0, stream>>>((int*)zbase, zn);

  edge_hist<<<(ET + 255) / 256, 256, 0, stream>>>(ei, E, N, counts);
  scan_counts<<<1, 1024, 0, stream>>>(counts, row_ptr, cursor, N);
  edge_scatter<<<(ET + 255) / 256, 256, 0, stream>>>(ei, E, N, cursor, colb);

  convert_x<<<(N * 64 + 255) / 256, 256, 0, stream>>>(x, A2, N);
  for (int p = 0; p < P; ++p) {
    convert_w<<<dim3((2 * W + 255) / 256, 256), 256, 0, stream>>>(w1_l, w1_r, B3, p * W, W);
    gemm_mfma<<<dim3(2 * W / 128, (N + 127) / 128), 256, 0, stream>>>(A2, B3, xlrp, N, 2 * W);
    conv1_attn<<<N, W / 8, 0, stream>>>(xlrp, row_ptr, colb,
                                        att1 + p * W, b1 + p * W, h1 + p * W, W);
  }

  bn1_stats<<<dim3(4, 64), 256, 0, stream>>>(h1, bn1_sum, bn1_sq, N);
  bn1_proj<<<N, 256, 0, stream>>>(h1, bn1_sum, bn1_sq, g1, be1, w2_l, w2_r, xl2, xr2, N);
  conv2_attn<<<(N + 255) / 256, 256, 0, stream>>>(xl2, xr2, row_ptr, colb, att2, b2, out2, N);
  bn2_stats<<<(N + 255) / 256, 256, 0, stream>>>(out2, bn2acc, N);
  bn2_pool<<<(N + 255) / 256, 256, 0, stream>>>(out2, bn2acc, g2, be2, batch, pool_sum, pool_cnt, N);
  head_mlp<<<1, 64, 0, stream>>>(pool_sum, pool_cnt, lw1, lb1, lw2, lb2, (float*)d_out);
}